// Round 6
// baseline (715.237 us; speedup 1.0000x reference)
//
#include <hip/hip_runtime.h>
#include <math.h>

#define CH 128
#define BSHIFT 9                  // 512 nodes per bucket
#define BNODES (1 << BSHIFT)
#define CHUNKE 16384              // edges per hist/scatter block

typedef __attribute__((ext_vector_type(8))) short bf16x8;
typedef __attribute__((ext_vector_type(4))) float f32x4;

// ---------------- CSR build: atomic-free counting sort ----------------
__global__ __launch_bounds__(256) void hist_kernel(const int* __restrict__ pe,
                                                   const int* __restrict__ ne,
                                                   int* __restrict__ hb,
                                                   int NBr, int G, int M, int E) {
    const int g = blockIdx.x, s = blockIdx.y, t = threadIdx.x;
    const int* __restrict__ dst = (s ? ne : pe) + E;
    __shared__ int h[512];                      // NBr <= 512
    for (int i = t; i < NBr; i += 256) h[i] = 0;
    __syncthreads();
    const int e0 = g * CHUNKE, e1 = min(e0 + CHUNKE, E);
    for (int e = e0 + t; e < e1; e += 256) atomicAdd(&h[dst[e] >> BSHIFT], 1);
    __syncthreads();
    int* out = hb + (size_t)s * M;
    for (int b = t; b < NBr; b += 256) out[b * G + g] = h[b];
}

__global__ __launch_bounds__(1024) void hscan_kernel(int* __restrict__ hb, int M) {
    const int s = blockIdx.y, t = threadIdx.x;
    int* H = hb + (size_t)s * M;
    const int K = (M + 1023) >> 10;
    const int i0 = t * K, i1 = min(i0 + K, M);
    int sum = 0;
    for (int i = i0; i < i1; ++i) sum += H[i];
    __shared__ int sh[1024];
    sh[t] = sum;
    __syncthreads();
    for (int off = 1; off < 1024; off <<= 1) {
        int v = (t >= off) ? sh[t - off] : 0;
        __syncthreads();
        sh[t] += v;
        __syncthreads();
    }
    int run = sh[t] - sum;
    for (int i = i0; i < i1; ++i) { int v = H[i]; H[i] = run; run += v; }
}

__global__ __launch_bounds__(256) void scatter_kernel(const int* __restrict__ pe,
                                                      const int* __restrict__ ne,
                                                      const int* __restrict__ hb,
                                                      int* __restrict__ tmp,
                                                      int NBr, int G, int M, int E) {
    const int g = blockIdx.x, s = blockIdx.y, t = threadIdx.x;
    const int* __restrict__ ed = s ? ne : pe;
    const int* off = hb + (size_t)s * M;
    __shared__ int cur[512];
    for (int b = t; b < NBr; b += 256) cur[b] = off[b * G + g];
    __syncthreads();
    int* out = tmp + (size_t)s * E;
    const int e0 = g * CHUNKE, e1 = min(e0 + CHUNKE, E);
    for (int e = e0 + t; e < e1; e += 256) {
        const int src = ed[e], d = ed[E + e];
        const int p = atomicAdd(&cur[d >> BSHIFT], 1);   // LDS atomic
        out[p] = (src << BSHIFT) | (d & (BNODES - 1));
    }
}

__global__ __launch_bounds__(256) void bucket_kernel(const int* __restrict__ tmp,
                                                     const int* __restrict__ hb,
                                                     int* __restrict__ row_p,
                                                     int* __restrict__ row_n,
                                                     int* __restrict__ csr_p,
                                                     int* __restrict__ csr_n,
                                                     int NBr, int G, int M, int E, int nN) {
    const int b = blockIdx.x, s = blockIdx.y, t = threadIdx.x;
    const int* off = hb + (size_t)s * M;
    const int lo = off[b * G];
    const int hi = (b + 1 < NBr) ? off[(b + 1) * G] : E;
    const int base = b << BSHIFT;
    const int nloc = min(BNODES, nN - base);
    const int* __restrict__ in = tmp + (size_t)s * E;
    int* __restrict__ row = s ? row_n : row_p;
    int* __restrict__ csr = s ? csr_n : csr_p;
    __shared__ int cnt[BNODES];
    __shared__ int psum[256];
    for (int i = t; i < BNODES; i += 256) cnt[i] = 0;
    __syncthreads();
    for (int e = lo + t; e < hi; e += 256) atomicAdd(&cnt[in[e] & (BNODES - 1)], 1);
    __syncthreads();
    const int c0 = cnt[2 * t], c1 = cnt[2 * t + 1];
    const int ps = c0 + c1;
    psum[t] = ps;
    __syncthreads();
    for (int o = 1; o < 256; o <<= 1) {
        int v = (t >= o) ? psum[t - o] : 0;
        __syncthreads();
        psum[t] += v;
        __syncthreads();
    }
    const int ex = psum[t] - ps;
    cnt[2 * t]     = lo + ex;        // becomes write cursor
    cnt[2 * t + 1] = lo + ex + c0;
    if (2 * t < nloc)     row[base + 2 * t] = lo + ex;
    if (2 * t + 1 < nloc) row[base + 2 * t + 1] = lo + ex + c0;
    if (b == NBr - 1 && t == 0) row[nN] = E;
    __syncthreads();
    for (int e = lo + t; e < hi; e += 256) {
        const int v = in[e];
        const int p = atomicAdd(&cnt[v & (BNODES - 1)], 1);  // LDS atomic
        csr[p] = (v >> BSHIFT) << 8;   // BYTE offset of the 256B bf16 row
    }
}

// ---------------- helpers ----------------
__device__ __forceinline__ float fast_tanh(float x) {
    float e = __expf(2.0f * x);
    return 1.0f - 2.0f * __builtin_amdgcn_rcpf(e + 1.0f);
}

__device__ __forceinline__ unsigned short f2bf(float f) {  // RNE
    unsigned u = __float_as_uint(f);
    u += 0x7fffu + ((u >> 16) & 1u);
    return (unsigned short)(u >> 16);
}

__device__ __forceinline__ float bf_lo(unsigned v) { return __uint_as_float(v << 16); }
__device__ __forceinline__ float bf_hi(unsigned v) { return __uint_as_float(v & 0xffff0000u); }

// ---------------- x -> bf16 convert (once) ----------------
__global__ __launch_bounds__(256) void cvt_kernel(const float* __restrict__ x,
                                                  unsigned short* __restrict__ xb,
                                                  int total8) {
    const int i = blockIdx.x * 256 + threadIdx.x;
    if (i >= total8) return;
    const float4 u0 = ((const float4*)x)[2 * i];
    const float4 u1 = ((const float4*)x)[2 * i + 1];
    union { bf16x8 v; unsigned short u[8]; } o;
    o.u[0] = f2bf(u0.x); o.u[1] = f2bf(u0.y); o.u[2] = f2bf(u0.z); o.u[3] = f2bf(u0.w);
    o.u[4] = f2bf(u1.x); o.u[5] = f2bf(u1.y); o.u[6] = f2bf(u1.z); o.u[7] = f2bf(u1.w);
    ((bf16x8*)xb)[i] = o.v;
}

// ---------------- aggregate ----------------
// One wave per node, both signs interleaved. csr holds BYTE offsets so the
// gather is saddr-form: base SGPR pair + 32-bit voffset (1 v_add per row).
// float2 accumulators -> v_pk_add_f32. Next iteration's csr offsets are
// prefetched under the row gathers (wave-uniform branch).
#define RD8(csr, e, acc) { \
    const int o0=csr[e],o1=csr[e+1],o2=csr[e+2],o3=csr[e+3]; \
    const int o4=csr[e+4],o5=csr[e+5],o6=csr[e+6],o7=csr[e+7]; \
    const unsigned w0=*(const unsigned*)(fB+o0+lane4); \
    const unsigned w1=*(const unsigned*)(fB+o1+lane4); \
    const unsigned w2=*(const unsigned*)(fB+o2+lane4); \
    const unsigned w3=*(const unsigned*)(fB+o3+lane4); \
    const unsigned w4=*(const unsigned*)(fB+o4+lane4); \
    const unsigned w5=*(const unsigned*)(fB+o5+lane4); \
    const unsigned w6=*(const unsigned*)(fB+o6+lane4); \
    const unsigned w7=*(const unsigned*)(fB+o7+lane4); \
    acc.x += ((bf_lo(w0)+bf_lo(w1))+(bf_lo(w2)+bf_lo(w3))) + \
             ((bf_lo(w4)+bf_lo(w5))+(bf_lo(w6)+bf_lo(w7))); \
    acc.y += ((bf_hi(w0)+bf_hi(w1))+(bf_hi(w2)+bf_hi(w3))) + \
             ((bf_hi(w4)+bf_hi(w5))+(bf_hi(w6)+bf_hi(w7))); }

#define RD4(csr, e, acc) { \
    const int o0=csr[e],o1=csr[e+1],o2=csr[e+2],o3=csr[e+3]; \
    const unsigned w0=*(const unsigned*)(fB+o0+lane4); \
    const unsigned w1=*(const unsigned*)(fB+o1+lane4); \
    const unsigned w2=*(const unsigned*)(fB+o2+lane4); \
    const unsigned w3=*(const unsigned*)(fB+o3+lane4); \
    acc.x += (bf_lo(w0)+bf_lo(w1))+(bf_lo(w2)+bf_lo(w3)); \
    acc.y += (bf_hi(w0)+bf_hi(w1))+(bf_hi(w2)+bf_hi(w3)); }

#define RD1(csr, e, acc) { \
    const unsigned w0=*(const unsigned*)(fB+csr[e]+lane4); \
    acc.x += bf_lo(w0); acc.y += bf_hi(w0); }

__global__ __launch_bounds__(256) void agg_kernel(
    const unsigned short* __restrict__ feat,
    unsigned* __restrict__ aggp, unsigned* __restrict__ aggn,
    const int* __restrict__ row_p, const int* __restrict__ csr_p,
    const int* __restrict__ row_n, const int* __restrict__ csr_n, int nN) {
    const int t = threadIdx.x;
    const int wave = t >> 6;
    const int lane = t & 63;
    const int node = blockIdx.x * 4 + wave;
    if (node >= nN) return;
    const char* __restrict__ fB = (const char*)feat;
    const int lane4 = lane * 4;
    int ep = row_p[node]; const int e1p = row_p[node + 1];
    int en = row_n[node]; const int e1n = row_n[node + 1];
    const int degp = e1p - ep;
    const int degn = e1n - en;
    float2 ap = {0.f, 0.f}, an = {0.f, 0.f};

    // joint main: 16 row gathers in flight, next csr offsets prefetched
    int obP[8], obN[8];
    bool have = (ep + 8 <= e1p) && (en + 8 <= e1n);
    if (have) {
#pragma unroll
        for (int j = 0; j < 8; ++j) { obP[j] = csr_p[ep + j]; obN[j] = csr_n[en + j]; }
    }
    while (have) {
        unsigned wp[8], wn[8];
#pragma unroll
        for (int j = 0; j < 8; ++j) wp[j] = *(const unsigned*)(fB + obP[j] + lane4);
#pragma unroll
        for (int j = 0; j < 8; ++j) wn[j] = *(const unsigned*)(fB + obN[j] + lane4);
        ep += 8; en += 8;
        have = (ep + 8 <= e1p) && (en + 8 <= e1n);
        if (have) {
#pragma unroll
            for (int j = 0; j < 8; ++j) { obP[j] = csr_p[ep + j]; obN[j] = csr_n[en + j]; }
        }
#pragma unroll
        for (int j = 0; j < 8; ++j) { ap.x += bf_lo(wp[j]); ap.y += bf_hi(wp[j]); }
#pragma unroll
        for (int j = 0; j < 8; ++j) { an.x += bf_lo(wn[j]); an.y += bf_hi(wn[j]); }
    }
    // per-sign drains
    for (; ep + 7 < e1p; ep += 8) RD8(csr_p, ep, ap);
    if (ep + 3 < e1p) { RD4(csr_p, ep, ap); ep += 4; }
    for (; ep < e1p; ++ep) RD1(csr_p, ep, ap);
    for (; en + 7 < e1n; en += 8) RD8(csr_n, en, an);
    if (en + 3 < e1n) { RD4(csr_n, en, an); en += 4; }
    for (; en < e1n; ++en) RD1(csr_n, en, an);

    const float invp = 1.0f / (float)(degp > 1 ? degp : 1);
    const float invn = 1.0f / (float)(degn > 1 ? degn : 1);
    aggp[(size_t)node * 64 + lane] = (unsigned)f2bf(ap.x * invp) | ((unsigned)f2bf(ap.y * invp) << 16);
    aggn[(size_t)node * 64 + lane] = (unsigned)f2bf(an.x * invn) | ((unsigned)f2bf(an.y * invn) << 16);
}

// ---------------- weight packing ----------------
__global__ __launch_bounds__(64) void wpack_kernel(
    const float* __restrict__ Wp_l, const float* __restrict__ Wp_r,
    const float* __restrict__ Wn_l, const float* __restrict__ Wn_r,
    const float* __restrict__ Wl_pos, const float* __restrict__ Wr_pos,
    const float* __restrict__ Wl_neg, const float* __restrict__ Wr_neg,
    unsigned short* __restrict__ Wpk) {
    const int b = blockIdx.x;  // 0..287 = L*96 + ks*8 + nt
    const int L = b / 96;
    const int rem = b % 96;
    const int ks = rem / 8, nt = rem % 8;
    const int lane = threadIdx.x;
    const int kb = ks * 32 + (lane >> 4) * 8;
    const int n = nt * 16 + (lane & 15);
    unsigned short v[8];
#pragma unroll
    for (int j = 0; j < 8; ++j) {
        const int k = kb + j;
        float w = 0.f;
        if (L == 0) {
            if (k < 128)      w = (n < 64) ? Wp_l[k * 64 + n] : 0.f;
            else if (k < 256) w = (n < 64) ? 0.f : Wn_l[(k - 128) * 64 + (n - 64)];
            else              w = (n < 64) ? Wp_r[(k - 256) * 64 + n]
                                           : Wn_r[(k - 256) * 64 + (n - 64)];
        } else {
            const float* WLp = Wl_pos + (size_t)(L - 1) * 128 * 64;
            const float* WLn = Wl_neg + (size_t)(L - 1) * 128 * 64;
            const float* WRp = Wr_pos + (size_t)(L - 1) * 64 * 64;
            const float* WRn = Wr_neg + (size_t)(L - 1) * 64 * 64;
            if (k < 64)       w = (n < 64) ? WLp[k * 64 + n] : 0.f;
            else if (k < 128) w = (n < 64) ? 0.f : WLn[(k - 64) * 64 + (n - 64)];
            else if (k < 192) w = (n < 64) ? 0.f : WLn[(64 + k - 128) * 64 + (n - 64)];
            else if (k < 256) w = (n < 64) ? WLp[(64 + k - 192) * 64 + n] : 0.f;
            else if (k < 320) w = (n < 64) ? WRp[(k - 256) * 64 + n] : 0.f;
            else              w = (n < 64) ? 0.f : WRn[(k - 320) * 64 + (n - 64)];
        }
        v[j] = f2bf(w);
    }
    unsigned short* dst = Wpk + (size_t)b * 512 + lane * 8;
#pragma unroll
    for (int j = 0; j < 8; ++j) dst[j] = v[j];
}

__global__ void bcat_kernel(const float* __restrict__ bp, const float* __restrict__ bn,
                            const float* __restrict__ b_pos, const float* __restrict__ b_neg,
                            float* __restrict__ bcat) {
    int t = threadIdx.x;  // 384
    int L = t >> 7, n = t & 127;
    float v;
    if (L == 0) v = (n < 64) ? bp[n] : bn[n - 64];
    else        v = (n < 64) ? b_pos[(L - 1) * 64 + n] : b_neg[(L - 1) * 64 + (n - 64)];
    bcat[t] = v;
}

// ---------------- MFMA GEMM: z = tanh([aggp|aggn|feat] @ Wcat + bcat) ----------------
// All inputs bf16 (xb pre-converted). In-place safe per 16-row wave band.
template <bool OUTF32>
__global__ __launch_bounds__(256) void gemm_kernel(
    const unsigned short* __restrict__ aggp, const unsigned short* __restrict__ aggn,
    const unsigned short* __restrict__ feat, const unsigned short* __restrict__ Wpk,
    const float* __restrict__ bcat, void* __restrict__ outv, int nN) {
    const int t = threadIdx.x;
    const int wave = __builtin_amdgcn_readfirstlane(t >> 6);
    const int lane = t & 63;
    const int r0 = blockIdx.x * 64 + wave * 16;
    int rowA = r0 + (lane & 15);
    if (rowA >= nN) rowA = nN - 1;  // clamp loads; stores guarded
    const int koff = (lane >> 4) * 8;

    f32x4 acc[8];
#pragma unroll
    for (int i = 0; i < 8; ++i) acc[i] = (f32x4){0.f, 0.f, 0.f, 0.f};

#pragma unroll
    for (int ks = 0; ks < 12; ++ks) {
        const int kcol = (ks & 3) * 32 + koff;
        const unsigned short* ap = (ks < 4) ? aggp : (ks < 8) ? aggn : feat;
        const bf16x8 a = *(const bf16x8*)(ap + (size_t)rowA * CH + kcol);
        const unsigned short* wb = Wpk + (size_t)(ks * 8) * 512 + lane * 8;
#pragma unroll
        for (int nt = 0; nt < 8; ++nt) {
            const bf16x8 bfr = *(const bf16x8*)(wb + nt * 512);
            acc[nt] = __builtin_amdgcn_mfma_f32_16x16x32_bf16(a, bfr, acc[nt], 0, 0, 0);
        }
    }

    const int col0 = lane & 15;
    const int rq = (lane >> 4) * 4;
#pragma unroll
    for (int nt = 0; nt < 8; ++nt) {
        const int col = nt * 16 + col0;
        const float bias = bcat[col];
#pragma unroll
        for (int r = 0; r < 4; ++r) {
            const int row = r0 + rq + r;
            if (row < nN) {
                const float v = fast_tanh(acc[nt][r] + bias);
                if (OUTF32) ((float*)outv)[(size_t)row * CH + col] = v;
                else ((unsigned short*)outv)[(size_t)row * CH + col] = f2bf(v);
            }
        }
    }
}

// ---------------- launch ----------------
extern "C" void kernel_launch(void* const* d_in, const int* in_sizes, int n_in,
                              void* d_out, int out_size, void* d_ws, size_t ws_size,
                              hipStream_t stream) {
    const float* x      = (const float*)d_in[0];
    const int*   pe     = (const int*)d_in[1];  // [2][E] src,dst
    const int*   ne     = (const int*)d_in[2];
    const float* Wp_l   = (const float*)d_in[3];
    const float* Wp_r   = (const float*)d_in[4];
    const float* bp     = (const float*)d_in[5];
    const float* Wn_l   = (const float*)d_in[6];
    const float* Wn_r   = (const float*)d_in[7];
    const float* bn     = (const float*)d_in[8];
    const float* Wl_pos = (const float*)d_in[9];
    const float* Wr_pos = (const float*)d_in[10];
    const float* b_pos  = (const float*)d_in[11];
    const float* Wl_neg = (const float*)d_in[12];
    const float* Wr_neg = (const float*)d_in[13];
    const float* b_neg  = (const float*)d_in[14];

    const int E = in_sizes[1] / 2;
    const int n = in_sizes[0] / CH;

    const int NBr = (n + BNODES - 1) >> BSHIFT;        // buckets per sign (196)
    const int G   = (E + CHUNKE - 1) / CHUNKE;         // chunks per sign (74)
    const int M   = NBr * G;                           // hist entries per sign

    // workspace layout
    unsigned short* A    = (unsigned short*)d_ws;   // n*128 bf16
    unsigned short* B    = A + (size_t)n * CH;
    unsigned short* C    = B + (size_t)n * CH;
    unsigned short* Wpk  = C + (size_t)n * CH;      // 3*96*512 = 147456
    float* bcat  = (float*)(Wpk + 147456);          // 384
    int* row_p   = (int*)(bcat + 384);              // n+1
    int* row_n   = row_p + n + 1;                   // n+1
    int* csr_p   = row_n + n + 1;                   // E (byte offsets)
    int* csr_n   = csr_p + E;                       // E (byte offsets)
    int* hb      = csr_n + E;                       // 2*M
    // packed edge temp (2E ints) aliases C during CSR build; afterwards the
    // same region holds xb (bf16 of x) until gemm0 completes; then C becomes
    // the L1 agg output. All transitions stream-ordered -> safe.
    int* tmp     = (int*)C;
    unsigned short* xb = C;

    // CSR build: no global atomics, no memset
    hist_kernel<<<dim3(G, 2), 256, 0, stream>>>(pe, ne, hb, NBr, G, M, E);
    wpack_kernel<<<288, 64, 0, stream>>>(Wp_l, Wp_r, Wn_l, Wn_r,
                                         Wl_pos, Wr_pos, Wl_neg, Wr_neg, Wpk);
    bcat_kernel<<<1, 384, 0, stream>>>(bp, bn, b_pos, b_neg, bcat);
    hscan_kernel<<<dim3(1, 2), 1024, 0, stream>>>(hb, M);
    scatter_kernel<<<dim3(G, 2), 256, 0, stream>>>(pe, ne, hb, tmp, NBr, G, M, E);
    bucket_kernel<<<dim3(NBr, 2), 256, 0, stream>>>(tmp, hb, row_p, row_n,
                                                    csr_p, csr_n, NBr, G, M, E, n);
    // x -> bf16 (after CSR build so xb can overwrite tmp)
    const int total8 = n * CH / 8;
    cvt_kernel<<<(total8 + 255) / 256, 256, 0, stream>>>(x, xb, total8);

    const dim3 agrid((n + 3) / 4), ablock(256);
    const dim3 ggrid((n + 63) / 64), gblock(256);

    // L0: agg(xb) -> A,B ; gemm(A,B,xb) -> z1 in A
    agg_kernel<<<agrid, ablock, 0, stream>>>(
        xb, (unsigned*)A, (unsigned*)B, row_p, csr_p, row_n, csr_n, n);
    gemm_kernel<false><<<ggrid, gblock, 0, stream>>>(
        A, B, xb, Wpk, bcat, A, n);
    // L1: agg(A) -> B,C ; gemm(B,C,A) -> z2 in B
    agg_kernel<<<agrid, ablock, 0, stream>>>(
        A, (unsigned*)B, (unsigned*)C, row_p, csr_p, row_n, csr_n, n);
    gemm_kernel<false><<<ggrid, gblock, 0, stream>>>(
        B, C, A, Wpk + 96 * 512, bcat + 128, B, n);
    // L2: agg(B) -> A,C ; gemm(A,C,B) -> d_out fp32
    agg_kernel<<<agrid, ablock, 0, stream>>>(
        B, (unsigned*)A, (unsigned*)C, row_p, csr_p, row_n, csr_n, n);
    gemm_kernel<true><<<ggrid, gblock, 0, stream>>>(
        A, C, B, Wpk + 2 * 96 * 512, bcat + 256, d_out, n);
}

// Round 7
// 618.393 us; speedup vs baseline: 1.1566x; 1.1566x over previous
//
#include <hip/hip_runtime.h>
#include <math.h>

#define CH 128
#define BSHIFT 9                  // 512 nodes per bucket
#define BNODES (1 << BSHIFT)
#define CHUNKE 16384              // edges per hist/scatter block

typedef __attribute__((ext_vector_type(8))) short bf16x8;
typedef __attribute__((ext_vector_type(4))) float f32x4;

// ---------------- CSR build: atomic-free counting sort ----------------
__global__ __launch_bounds__(256) void hist_kernel(const int* __restrict__ pe,
                                                   const int* __restrict__ ne,
                                                   int* __restrict__ hb,
                                                   int NBr, int G, int M, int E) {
    const int g = blockIdx.x, s = blockIdx.y, t = threadIdx.x;
    const int* __restrict__ dst = (s ? ne : pe) + E;
    __shared__ int h[512];                      // NBr <= 512
    for (int i = t; i < NBr; i += 256) h[i] = 0;
    __syncthreads();
    const int e0 = g * CHUNKE, e1 = min(e0 + CHUNKE, E);
    for (int e = e0 + t; e < e1; e += 256) atomicAdd(&h[dst[e] >> BSHIFT], 1);
    __syncthreads();
    int* out = hb + (size_t)s * M;
    for (int b = t; b < NBr; b += 256) out[b * G + g] = h[b];
}

__global__ __launch_bounds__(1024) void hscan_kernel(int* __restrict__ hb, int M) {
    const int s = blockIdx.y, t = threadIdx.x;
    int* H = hb + (size_t)s * M;
    const int K = (M + 1023) >> 10;
    const int i0 = t * K, i1 = min(i0 + K, M);
    int sum = 0;
    for (int i = i0; i < i1; ++i) sum += H[i];
    __shared__ int sh[1024];
    sh[t] = sum;
    __syncthreads();
    for (int off = 1; off < 1024; off <<= 1) {
        int v = (t >= off) ? sh[t - off] : 0;
        __syncthreads();
        sh[t] += v;
        __syncthreads();
    }
    int run = sh[t] - sum;
    for (int i = i0; i < i1; ++i) { int v = H[i]; H[i] = run; run += v; }
}

__global__ __launch_bounds__(256) void scatter_kernel(const int* __restrict__ pe,
                                                      const int* __restrict__ ne,
                                                      const int* __restrict__ hb,
                                                      int* __restrict__ tmp,
                                                      int NBr, int G, int M, int E) {
    const int g = blockIdx.x, s = blockIdx.y, t = threadIdx.x;
    const int* __restrict__ ed = s ? ne : pe;
    const int* off = hb + (size_t)s * M;
    __shared__ int cur[512];
    for (int b = t; b < NBr; b += 256) cur[b] = off[b * G + g];
    __syncthreads();
    int* out = tmp + (size_t)s * E;
    const int e0 = g * CHUNKE, e1 = min(e0 + CHUNKE, E);
    for (int e = e0 + t; e < e1; e += 256) {
        const int src = ed[e], d = ed[E + e];
        const int p = atomicAdd(&cur[d >> BSHIFT], 1);   // LDS atomic
        out[p] = (src << BSHIFT) | (d & (BNODES - 1));
    }
}

__global__ __launch_bounds__(256) void bucket_kernel(const int* __restrict__ tmp,
                                                     const int* __restrict__ hb,
                                                     int* __restrict__ row_p,
                                                     int* __restrict__ row_n,
                                                     int* __restrict__ csr_p,
                                                     int* __restrict__ csr_n,
                                                     int NBr, int G, int M, int E, int nN) {
    const int b = blockIdx.x, s = blockIdx.y, t = threadIdx.x;
    const int* off = hb + (size_t)s * M;
    const int lo = off[b * G];
    const int hi = (b + 1 < NBr) ? off[(b + 1) * G] : E;
    const int base = b << BSHIFT;
    const int nloc = min(BNODES, nN - base);
    const int* __restrict__ in = tmp + (size_t)s * E;
    int* __restrict__ row = s ? row_n : row_p;
    int* __restrict__ csr = s ? csr_n : csr_p;
    __shared__ int cnt[BNODES];
    __shared__ int psum[256];
    for (int i = t; i < BNODES; i += 256) cnt[i] = 0;
    __syncthreads();
    for (int e = lo + t; e < hi; e += 256) atomicAdd(&cnt[in[e] & (BNODES - 1)], 1);
    __syncthreads();
    const int c0 = cnt[2 * t], c1 = cnt[2 * t + 1];
    const int ps = c0 + c1;
    psum[t] = ps;
    __syncthreads();
    for (int o = 1; o < 256; o <<= 1) {
        int v = (t >= o) ? psum[t - o] : 0;
        __syncthreads();
        psum[t] += v;
        __syncthreads();
    }
    const int ex = psum[t] - ps;
    cnt[2 * t]     = lo + ex;        // becomes write cursor
    cnt[2 * t + 1] = lo + ex + c0;
    if (2 * t < nloc)     row[base + 2 * t] = lo + ex;
    if (2 * t + 1 < nloc) row[base + 2 * t + 1] = lo + ex + c0;
    if (b == NBr - 1 && t == 0) row[nN] = E;
    __syncthreads();
    for (int e = lo + t; e < hi; e += 256) {
        const int v = in[e];
        const int p = atomicAdd(&cnt[v & (BNODES - 1)], 1);  // LDS atomic
        csr[p] = (v >> BSHIFT) << 8;   // BYTE offset of the 256B bf16 row
    }
}

// ---------------- helpers ----------------
__device__ __forceinline__ float fast_tanh(float x) {
    float e = __expf(2.0f * x);
    return 1.0f - 2.0f * __builtin_amdgcn_rcpf(e + 1.0f);
}

__device__ __forceinline__ unsigned short f2bf(float f) {  // RNE
    unsigned u = __float_as_uint(f);
    u += 0x7fffu + ((u >> 16) & 1u);
    return (unsigned short)(u >> 16);
}

__device__ __forceinline__ float bf_lo(unsigned v) { return __uint_as_float(v << 16); }
__device__ __forceinline__ float bf_hi(unsigned v) { return __uint_as_float(v & 0xffff0000u); }

// ---------------- x -> bf16 convert (once) ----------------
__global__ __launch_bounds__(256) void cvt_kernel(const float* __restrict__ x,
                                                  unsigned short* __restrict__ xb,
                                                  int total8) {
    const int i = blockIdx.x * 256 + threadIdx.x;
    if (i >= total8) return;
    const float4 u0 = ((const float4*)x)[2 * i];
    const float4 u1 = ((const float4*)x)[2 * i + 1];
    union { bf16x8 v; unsigned short u[8]; } o;
    o.u[0] = f2bf(u0.x); o.u[1] = f2bf(u0.y); o.u[2] = f2bf(u0.z); o.u[3] = f2bf(u0.w);
    o.u[4] = f2bf(u1.x); o.u[5] = f2bf(u1.y); o.u[6] = f2bf(u1.z); o.u[7] = f2bf(u1.w);
    ((bf16x8*)xb)[i] = o.v;
}

// ---------------- aggregate ----------------
// One wave per node, both signs interleaved (round-5 structure: compiler-
// scheduled G8 macros, accumulate in-macro -> low VGPR, 8 waves/SIMD).
// csr holds BYTE offsets (written by bucket_kernel) -> 1 v_add per gather.
// Row bounds readfirstlane'd to SGPR -> csr index reads become s_load.
#define G8(csr, e, ax, ay) { \
    const int o0=csr[e],o1=csr[e+1],o2=csr[e+2],o3=csr[e+3]; \
    const int o4=csr[e+4],o5=csr[e+5],o6=csr[e+6],o7=csr[e+7]; \
    const unsigned w0=*(const unsigned*)(fB+o0+lane4); \
    const unsigned w1=*(const unsigned*)(fB+o1+lane4); \
    const unsigned w2=*(const unsigned*)(fB+o2+lane4); \
    const unsigned w3=*(const unsigned*)(fB+o3+lane4); \
    const unsigned w4=*(const unsigned*)(fB+o4+lane4); \
    const unsigned w5=*(const unsigned*)(fB+o5+lane4); \
    const unsigned w6=*(const unsigned*)(fB+o6+lane4); \
    const unsigned w7=*(const unsigned*)(fB+o7+lane4); \
    ax += ((bf_lo(w0)+bf_lo(w1))+(bf_lo(w2)+bf_lo(w3))) + \
          ((bf_lo(w4)+bf_lo(w5))+(bf_lo(w6)+bf_lo(w7))); \
    ay += ((bf_hi(w0)+bf_hi(w1))+(bf_hi(w2)+bf_hi(w3))) + \
          ((bf_hi(w4)+bf_hi(w5))+(bf_hi(w6)+bf_hi(w7))); }

#define G4(csr, e, ax, ay) { \
    const int o0=csr[e],o1=csr[e+1],o2=csr[e+2],o3=csr[e+3]; \
    const unsigned w0=*(const unsigned*)(fB+o0+lane4); \
    const unsigned w1=*(const unsigned*)(fB+o1+lane4); \
    const unsigned w2=*(const unsigned*)(fB+o2+lane4); \
    const unsigned w3=*(const unsigned*)(fB+o3+lane4); \
    ax += (bf_lo(w0)+bf_lo(w1))+(bf_lo(w2)+bf_lo(w3)); \
    ay += (bf_hi(w0)+bf_hi(w1))+(bf_hi(w2)+bf_hi(w3)); }

#define G1(csr, e, ax, ay) { \
    const unsigned w0=*(const unsigned*)(fB+csr[e]+lane4); \
    ax += bf_lo(w0); ay += bf_hi(w0); }

__global__ __launch_bounds__(256) void agg_kernel(
    const unsigned short* __restrict__ feat,
    unsigned* __restrict__ aggp, unsigned* __restrict__ aggn,
    const int* __restrict__ row_p, const int* __restrict__ csr_p,
    const int* __restrict__ row_n, const int* __restrict__ csr_n, int nN) {
    const int t = threadIdx.x;
    const int wave = t >> 6;
    const int lane = t & 63;
    const int node = blockIdx.x * 4 + wave;
    if (node >= nN) return;
    const char* __restrict__ fB = (const char*)feat;
    const int lane4 = lane * 4;
    // wave-uniform bounds -> SGPR (uniform csr addresses -> s_load)
    int ep = __builtin_amdgcn_readfirstlane(row_p[node]);
    const int e1p = __builtin_amdgcn_readfirstlane(row_p[node + 1]);
    int en = __builtin_amdgcn_readfirstlane(row_n[node]);
    const int e1n = __builtin_amdgcn_readfirstlane(row_n[node + 1]);
    const int degp = e1p - ep;
    const int degn = e1n - en;
    float axp = 0.f, ayp = 0.f, axn = 0.f, ayn = 0.f;
    // joint main: 16 row gathers in flight
    while (ep + 8 <= e1p && en + 8 <= e1n) {
        G8(csr_p, ep, axp, ayp);
        G8(csr_n, en, axn, ayn);
        ep += 8; en += 8;
    }
    // joint mid: 8 in flight
    while (ep + 4 <= e1p && en + 4 <= e1n) {
        G4(csr_p, ep, axp, ayp);
        G4(csr_n, en, axn, ayn);
        ep += 4; en += 4;
    }
    // per-sign drains
    for (; ep + 7 < e1p; ep += 8) G8(csr_p, ep, axp, ayp);
    if (ep + 3 < e1p) { G4(csr_p, ep, axp, ayp); ep += 4; }
    for (; ep < e1p; ++ep) G1(csr_p, ep, axp, ayp);
    for (; en + 7 < e1n; en += 8) G8(csr_n, en, axn, ayn);
    if (en + 3 < e1n) { G4(csr_n, en, axn, ayn); en += 4; }
    for (; en < e1n; ++en) G1(csr_n, en, axn, ayn);

    const float invp = 1.0f / (float)(degp > 1 ? degp : 1);
    const float invn = 1.0f / (float)(degn > 1 ? degn : 1);
    aggp[(size_t)node * 64 + lane] = (unsigned)f2bf(axp * invp) | ((unsigned)f2bf(ayp * invp) << 16);
    aggn[(size_t)node * 64 + lane] = (unsigned)f2bf(axn * invn) | ((unsigned)f2bf(ayn * invn) << 16);
}

// ---------------- weight packing ----------------
__global__ __launch_bounds__(64) void wpack_kernel(
    const float* __restrict__ Wp_l, const float* __restrict__ Wp_r,
    const float* __restrict__ Wn_l, const float* __restrict__ Wn_r,
    const float* __restrict__ Wl_pos, const float* __restrict__ Wr_pos,
    const float* __restrict__ Wl_neg, const float* __restrict__ Wr_neg,
    unsigned short* __restrict__ Wpk) {
    const int b = blockIdx.x;  // 0..287 = L*96 + ks*8 + nt
    const int L = b / 96;
    const int rem = b % 96;
    const int ks = rem / 8, nt = rem % 8;
    const int lane = threadIdx.x;
    const int kb = ks * 32 + (lane >> 4) * 8;
    const int n = nt * 16 + (lane & 15);
    unsigned short v[8];
#pragma unroll
    for (int j = 0; j < 8; ++j) {
        const int k = kb + j;
        float w = 0.f;
        if (L == 0) {
            if (k < 128)      w = (n < 64) ? Wp_l[k * 64 + n] : 0.f;
            else if (k < 256) w = (n < 64) ? 0.f : Wn_l[(k - 128) * 64 + (n - 64)];
            else              w = (n < 64) ? Wp_r[(k - 256) * 64 + n]
                                           : Wn_r[(k - 256) * 64 + (n - 64)];
        } else {
            const float* WLp = Wl_pos + (size_t)(L - 1) * 128 * 64;
            const float* WLn = Wl_neg + (size_t)(L - 1) * 128 * 64;
            const float* WRp = Wr_pos + (size_t)(L - 1) * 64 * 64;
            const float* WRn = Wr_neg + (size_t)(L - 1) * 64 * 64;
            if (k < 64)       w = (n < 64) ? WLp[k * 64 + n] : 0.f;
            else if (k < 128) w = (n < 64) ? 0.f : WLn[(k - 64) * 64 + (n - 64)];
            else if (k < 192) w = (n < 64) ? 0.f : WLn[(64 + k - 128) * 64 + (n - 64)];
            else if (k < 256) w = (n < 64) ? WLp[(64 + k - 192) * 64 + n] : 0.f;
            else if (k < 320) w = (n < 64) ? WRp[(k - 256) * 64 + n] : 0.f;
            else              w = (n < 64) ? 0.f : WRn[(k - 320) * 64 + (n - 64)];
        }
        v[j] = f2bf(w);
    }
    unsigned short* dst = Wpk + (size_t)b * 512 + lane * 8;
#pragma unroll
    for (int j = 0; j < 8; ++j) dst[j] = v[j];
}

__global__ void bcat_kernel(const float* __restrict__ bp, const float* __restrict__ bn,
                            const float* __restrict__ b_pos, const float* __restrict__ b_neg,
                            float* __restrict__ bcat) {
    int t = threadIdx.x;  // 384
    int L = t >> 7, n = t & 127;
    float v;
    if (L == 0) v = (n < 64) ? bp[n] : bn[n - 64];
    else        v = (n < 64) ? b_pos[(L - 1) * 64 + n] : b_neg[(L - 1) * 64 + (n - 64)];
    bcat[t] = v;
}

// ---------------- MFMA GEMM: z = tanh([aggp|aggn|feat] @ Wcat + bcat) ----------------
// All inputs bf16 (xb pre-converted). In-place safe per 16-row wave band.
template <bool OUTF32>
__global__ __launch_bounds__(256) void gemm_kernel(
    const unsigned short* __restrict__ aggp, const unsigned short* __restrict__ aggn,
    const unsigned short* __restrict__ feat, const unsigned short* __restrict__ Wpk,
    const float* __restrict__ bcat, void* __restrict__ outv, int nN) {
    const int t = threadIdx.x;
    const int wave = __builtin_amdgcn_readfirstlane(t >> 6);
    const int lane = t & 63;
    const int r0 = blockIdx.x * 64 + wave * 16;
    int rowA = r0 + (lane & 15);
    if (rowA >= nN) rowA = nN - 1;  // clamp loads; stores guarded
    const int koff = (lane >> 4) * 8;

    f32x4 acc[8];
#pragma unroll
    for (int i = 0; i < 8; ++i) acc[i] = (f32x4){0.f, 0.f, 0.f, 0.f};

#pragma unroll
    for (int ks = 0; ks < 12; ++ks) {
        const int kcol = (ks & 3) * 32 + koff;
        const unsigned short* ap = (ks < 4) ? aggp : (ks < 8) ? aggn : feat;
        const bf16x8 a = *(const bf16x8*)(ap + (size_t)rowA * CH + kcol);
        const unsigned short* wb = Wpk + (size_t)(ks * 8) * 512 + lane * 8;
#pragma unroll
        for (int nt = 0; nt < 8; ++nt) {
            const bf16x8 bfr = *(const bf16x8*)(wb + nt * 512);
            acc[nt] = __builtin_amdgcn_mfma_f32_16x16x32_bf16(a, bfr, acc[nt], 0, 0, 0);
        }
    }

    const int col0 = lane & 15;
    const int rq = (lane >> 4) * 4;
#pragma unroll
    for (int nt = 0; nt < 8; ++nt) {
        const int col = nt * 16 + col0;
        const float bias = bcat[col];
#pragma unroll
        for (int r = 0; r < 4; ++r) {
            const int row = r0 + rq + r;
            if (row < nN) {
                const float v = fast_tanh(acc[nt][r] + bias);
                if (OUTF32) ((float*)outv)[(size_t)row * CH + col] = v;
                else ((unsigned short*)outv)[(size_t)row * CH + col] = f2bf(v);
            }
        }
    }
}

// ---------------- launch ----------------
extern "C" void kernel_launch(void* const* d_in, const int* in_sizes, int n_in,
                              void* d_out, int out_size, void* d_ws, size_t ws_size,
                              hipStream_t stream) {
    const float* x      = (const float*)d_in[0];
    const int*   pe     = (const int*)d_in[1];  // [2][E] src,dst
    const int*   ne     = (const int*)d_in[2];
    const float* Wp_l   = (const float*)d_in[3];
    const float* Wp_r   = (const float*)d_in[4];
    const float* bp     = (const float*)d_in[5];
    const float* Wn_l   = (const float*)d_in[6];
    const float* Wn_r   = (const float*)d_in[7];
    const float* bn     = (const float*)d_in[8];
    const float* Wl_pos = (const float*)d_in[9];
    const float* Wr_pos = (const float*)d_in[10];
    const float* b_pos  = (const float*)d_in[11];
    const float* Wl_neg = (const float*)d_in[12];
    const float* Wr_neg = (const float*)d_in[13];
    const float* b_neg  = (const float*)d_in[14];

    const int E = in_sizes[1] / 2;
    const int n = in_sizes[0] / CH;

    const int NBr = (n + BNODES - 1) >> BSHIFT;        // buckets per sign (196)
    const int G   = (E + CHUNKE - 1) / CHUNKE;         // chunks per sign (74)
    const int M   = NBr * G;                           // hist entries per sign

    // workspace layout
    unsigned short* A    = (unsigned short*)d_ws;   // n*128 bf16
    unsigned short* B    = A + (size_t)n * CH;
    unsigned short* C    = B + (size_t)n * CH;
    unsigned short* Wpk  = C + (size_t)n * CH;      // 3*96*512 = 147456
    float* bcat  = (float*)(Wpk + 147456);          // 384
    int* row_p   = (int*)(bcat + 384);              // n+1
    int* row_n   = row_p + n + 1;                   // n+1
    int* csr_p   = row_n + n + 1;                   // E (byte offsets)
    int* csr_n   = csr_p + E;                       // E (byte offsets)
    int* hb      = csr_n + E;                       // 2*M
    // packed edge temp (2E ints) aliases C during CSR build; afterwards the
    // same region holds xb (bf16 of x) until gemm0 completes; then C becomes
    // the L1 agg output. All transitions stream-ordered -> safe.
    int* tmp     = (int*)C;
    unsigned short* xb = C;

    // CSR build: no global atomics, no memset
    hist_kernel<<<dim3(G, 2), 256, 0, stream>>>(pe, ne, hb, NBr, G, M, E);
    wpack_kernel<<<288, 64, 0, stream>>>(Wp_l, Wp_r, Wn_l, Wn_r,
                                         Wl_pos, Wr_pos, Wl_neg, Wr_neg, Wpk);
    bcat_kernel<<<1, 384, 0, stream>>>(bp, bn, b_pos, b_neg, bcat);
    hscan_kernel<<<dim3(1, 2), 1024, 0, stream>>>(hb, M);
    scatter_kernel<<<dim3(G, 2), 256, 0, stream>>>(pe, ne, hb, tmp, NBr, G, M, E);
    bucket_kernel<<<dim3(NBr, 2), 256, 0, stream>>>(tmp, hb, row_p, row_n,
                                                    csr_p, csr_n, NBr, G, M, E, n);
    // x -> bf16 (after CSR build so xb can overwrite tmp)
    const int total8 = n * CH / 8;
    cvt_kernel<<<(total8 + 255) / 256, 256, 0, stream>>>(x, xb, total8);

    const dim3 agrid((n + 3) / 4), ablock(256);
    const dim3 ggrid((n + 63) / 64), gblock(256);

    // L0: agg(xb) -> A,B ; gemm(A,B,xb) -> z1 in A
    agg_kernel<<<agrid, ablock, 0, stream>>>(
        xb, (unsigned*)A, (unsigned*)B, row_p, csr_p, row_n, csr_n, n);
    gemm_kernel<false><<<ggrid, gblock, 0, stream>>>(
        A, B, xb, Wpk, bcat, A, n);
    // L1: agg(A) -> B,C ; gemm(B,C,A) -> z2 in B
    agg_kernel<<<agrid, ablock, 0, stream>>>(
        A, (unsigned*)B, (unsigned*)C, row_p, csr_p, row_n, csr_n, n);
    gemm_kernel<false><<<ggrid, gblock, 0, stream>>>(
        B, C, A, Wpk + 96 * 512, bcat + 128, B, n);
    // L2: agg(B) -> A,C ; gemm(A,C,B) -> d_out fp32
    agg_kernel<<<agrid, ablock, 0, stream>>>(
        B, (unsigned*)A, (unsigned*)C, row_p, csr_p, row_n, csr_n, n);
    gemm_kernel<true><<<ggrid, gblock, 0, stream>>>(
        A, C, B, Wpk + 2 * 96 * 512, bcat + 256, d_out, n);
}